// Round 9
// baseline (110.149 us; speedup 1.0000x reference)
//
#include <hip/hip_runtime.h>
#include <hip/hip_bf16.h>
#include <cstdint>

typedef float f32x4 __attribute__((ext_vector_type(4)));
typedef short bf16x8 __attribute__((ext_vector_type(8)));
typedef short short8 __attribute__((ext_vector_type(8)));

#define CIN   128
#define WIMG  56
#define HWSZ  3136      // 56*56
#define OCH   256
#define HP    58
#define WP    58

// ---- prep A: border-zero (456 blocks) + weight repack (1152 blocks), merged ----
__global__ void small_prep(const float* __restrict__ wsrc,
                           __hip_bfloat16* __restrict__ wb,
                           __hip_bfloat16* __restrict__ xb) {
    int bidx = blockIdx.x;
    if (bidx < 456) {
        int idx = bidx * 256 + threadIdx.x;   // 116736 = 32*228*16
        int c8  = idx & 15;
        int t   = idx >> 4;
        int b   = t / 228;
        int pos = t - b * 228;
        int h, w;
        if (pos < 58)       { h = 0;             w = pos; }
        else if (pos < 116) { h = 57;            w = pos - 58; }
        else if (pos < 172) { h = pos - 116 + 1; w = 0; }
        else                { h = pos - 172 + 1; w = 57; }
        uint4 z = {0, 0, 0, 0};
        *(uint4*)((char*)xb + (((size_t)(b * HP + h) * WP + w) * CIN + c8 * 8) * 2) = z;
    } else {
        int idx = (bidx - 456) * 256 + threadIdx.x;   // 294912 = 9*256*128
        int c    = idx & 127;
        int rest = idx >> 7;
        int o    = rest & 255;
        int ij   = rest >> 8;
        wb[idx] = __float2bfloat16(wsrc[((size_t)o * CIN + c) * 9 + ij]);
    }
}

// ---- prep B: x [B][C][H][W] f32 -> xb padded NHWC bf16 [B][58][58][128] ----
__global__ __launch_bounds__(256)
void cast_transpose_x(const float* __restrict__ x,
                      __hip_bfloat16* __restrict__ xb) {
    __shared__ float tile[64][33];
    const int hw0 = blockIdx.x * 32;
    const int c0  = blockIdx.y * 64;
    const int b   = blockIdx.z;

    const int lx = threadIdx.x & 31;
    const int lc = threadIdx.x >> 5;
    const float* src = x + ((size_t)(b * CIN + c0 + lc) * HWSZ) + hw0 + lx;
#pragma unroll
    for (int k = 0; k < 8; ++k)
        tile[lc + k * 8][lx] = src[(size_t)(k * 8) * HWSZ];
    __syncthreads();

    const int slot = threadIdx.x & 7;
    const int hwl  = threadIdx.x >> 3;
    int hw = hw0 + hwl;
    int h = hw / WIMG;
    int w = hw - h * WIMG;
    short8 v;
#pragma unroll
    for (int j = 0; j < 8; ++j) {
        __hip_bfloat16 hb = __float2bfloat16(tile[slot * 8 + j][hwl]);
        v[j] = *reinterpret_cast<short*>(&hb);
    }
    *(short8*)(xb + (((size_t)b * HP + (h + 1)) * WP + (w + 1)) * CIN + c0 + slot * 8) = v;
}

// ---- async global->LDS 16B ----
__device__ __forceinline__ void gload16(const void* g, void* l) {
    __builtin_amdgcn_global_load_lds(
        (const __attribute__((address_space(1))) unsigned*)g,
        (__attribute__((address_space(3))) unsigned*)l,
        16, 0, 0);
}

// ---- main: patch-resident implicit conv, phase-pipelined ----
// BM=224 (4 out rows), BN=256. Patch = 6 padded rows x 58 x 128ch bf16 = 89088 B,
// staged once; K-loop = 9 taps x 4 phases (c-chunk x k-half), barrier-free.
// Per phase: prefetch next phase's A (7 ds_read_b128, afA/afB ping-pong) and
// B (4 global b128, bqA/bqB ping-pong), then 28 MFMAs on current operands.
// Swizzle key = output-col w mod 8 (56%8==0 -> uniform over 16 lanes -> 2-way free).
__global__ __launch_bounds__(512, 2)
void conv_gemm(const __hip_bfloat16* __restrict__ xb,
               const __hip_bfloat16* __restrict__ wb,
               const float* __restrict__ bias,
               float* __restrict__ out) {
    extern __shared__ __attribute__((aligned(16))) char smem[];   // 89088 B

    const int tid = threadIdx.x;
    const int wv  = tid >> 6;
    const int ln  = tid & 63;

    int bid = blockIdx.x;
    bid = (bid & 7) * 56 + (bid >> 3);        // XCD swizzle: 448 = 8*56, bijective
    const int b   = bid / 14;                 // batch
    const int rg  = bid - b * 14;             // row-group (4 out rows)
    const int m0  = b * HWSZ + rg * 224;
    const int h0  = rg * 4;                   // padded input rows h0..h0+5

    // ---- stage patch: 348 pixels x 16 slots; source col pre-XOR'd by (w mod 8) ----
#pragma unroll
    for (int r = 0; r < 11; ++r) {
        int li = r * 512 + tid;
        if (li < 5568) {
            int pix  = li >> 4;
            int slot = li & 15;
            int lr = pix / 58;
            int lc2 = pix - lr * 58;          // patch col (= w + jj at read time)
            const char* src = (const char*)xb +
                ((((size_t)(b * HP + h0 + lr)) * WP + lc2) << 8) +
                ((slot ^ (lc2 & 7)) << 4);
            gload16(src, smem + (li << 4));
        }
    }

    // ---- compute-side constants ----
    const int wm  = wv >> 2;                  // 0..1 : rows [wm*112, +112)
    const int wn  = wv & 3;                   // 0..3 : cols [wn*64, +64)
    const int fr  = ln & 15;
    const int kby = (ln >> 4) * 16;           // 16B slot within 64B k-half

    int lpixI[7], lwv[7];
#pragma unroll
    for (int mi = 0; mi < 7; ++mi) {
        int lp = wm * 112 + mi * 16 + fr;     // 0..223
        int lh = lp / 56;
        int lw = lp - lh * 56;
        lpixI[mi] = lh * 58 + lw;
        lwv[mi]   = lw;
    }

    // per-lane B fragment base
    const __hip_bfloat16* bbase = wb + (wn * 64 + fr) * CIN + ((ln >> 4) << 3);

    f32x4 acc[7][4] = {};
    bf16x8 afA[7], afB[7], bqA[4], bqB[4];

#define LOADB4(dst, toff) do {                                                \
    _Pragma("unroll") for (int ni = 0; ni < 4; ++ni)                          \
        dst[ni] = *(const bf16x8*)(bbase + (toff) + ni * (16 * CIN));         \
} while (0)

#define DS7(dst, tapoff, colb, keyarr) do {                                   \
    _Pragma("unroll") for (int mi = 0; mi < 7; ++mi) {                        \
        int px = lpixI[mi] + (tapoff);                                        \
        dst[mi] = *(const bf16x8*)(smem + (px << 8) +                         \
                                   (((colb) + kby) ^ keyarr[mi]));            \
    }                                                                         \
} while (0)

#define MM28(af, bq) do {                                                     \
    _Pragma("unroll") for (int mi = 0; mi < 7; ++mi)                          \
    _Pragma("unroll") for (int ni = 0; ni < 4; ++ni)                          \
        acc[mi][ni] = __builtin_amdgcn_mfma_f32_16x16x32_bf16(                \
            af[mi], bq[ni], acc[mi][ni], 0, 0, 0);                            \
} while (0)

    __syncthreads();                          // patch staged (drains vmcnt)

    // ---- prologue: phase (tap0, c0, k0) operands ----
    int key7[7];
#pragma unroll
    for (int mi = 0; mi < 7; ++mi) key7[mi] = (lwv[mi] & 7) << 4;
    DS7(afA, 0, 0, key7);
    LOADB4(bqA, 0);

#pragma unroll 1
    for (int i = 0; i < 9; ++i) {
        const int ii = i / 3, jj = i - 3 * ii;
        const int tapoff = ii * 58 + jj;
        const int offB   = i * (OCH * CIN);
        const bool pf = (i < 8);

        // current-tap keys (jj-shifted w mod 8)
#pragma unroll
        for (int mi = 0; mi < 7; ++mi) key7[mi] = ((lwv[mi] + jj) & 7) << 4;

        // ph0: compute (c0,k0)=afA,bqA; prefetch (c0,k1)
        DS7(afB, tapoff, 64, key7);
        LOADB4(bqB, offB + 32);
        MM28(afA, bqA);

        // ph1: compute (c0,k1); prefetch (c1,k0)
        DS7(afA, tapoff, 128, key7);
        LOADB4(bqA, offB + 64);
        MM28(afB, bqB);

        // ph2: compute (c1,k0); prefetch (c1,k1)
        DS7(afB, tapoff, 192, key7);
        LOADB4(bqB, offB + 96);
        MM28(afA, bqA);

        // ph3: compute (c1,k1); prefetch next tap (c0,k0)
        if (pf) {
            const int i2  = i + 1;
            const int ii2 = i2 / 3, jj2 = i2 - 3 * ii2;
            const int tapoffN = ii2 * 58 + jj2;
            int keyN[7];
#pragma unroll
            for (int mi = 0; mi < 7; ++mi) keyN[mi] = ((lwv[mi] + jj2) & 7) << 4;
            DS7(afA, tapoffN, 0, keyN);
            LOADB4(bqA, offB + OCH * CIN);
        }
        MM28(afB, bqB);
    }
#undef LOADB4
#undef DS7
#undef MM28

    // ---- epilogue: C/D map col=ln&15 (n), row=(ln>>4)*4+reg (pixel) ----
    const int laneR4 = (ln >> 4) * 4;
    float bn[4];
#pragma unroll
    for (int ni = 0; ni < 4; ++ni)
        bn[ni] = bias[wn * 64 + ni * 16 + fr];

#pragma unroll
    for (int mi = 0; mi < 7; ++mi) {
        int p0 = m0 + wm * 112 + mi * 16 + laneR4;   // multiple of 4
        int hw = p0 - b * HWSZ;                      // within batch by construction
#pragma unroll
        for (int ni = 0; ni < 4; ++ni) {
            int n = wn * 64 + ni * 16 + fr;
            float4 v;
            v.x = acc[mi][ni][0] + bn[ni];
            v.y = acc[mi][ni][1] + bn[ni];
            v.z = acc[mi][ni][2] + bn[ni];
            v.w = acc[mi][ni][3] + bn[ni];
            *(float4*)(out + ((size_t)(b * OCH + n) * HWSZ + hw)) = v;
        }
    }
}

extern "C" void kernel_launch(void* const* d_in, const int* in_sizes, int n_in,
                              void* d_out, int out_size, void* d_ws, size_t ws_size,
                              hipStream_t stream) {
    const float* x    = (const float*)d_in[0];
    const float* w    = (const float*)d_in[1];
    const float* bias = (const float*)d_in[2];
    float* out = (float*)d_out;

    char* ws = (char*)d_ws;
    __hip_bfloat16* xbuf = (__hip_bfloat16*)ws;                   // 27,557,888 B
    __hip_bfloat16* wbuf = (__hip_bfloat16*)(ws + 27557888);      //    589,824 B

    hipFuncSetAttribute(reinterpret_cast<const void*>(conv_gemm),
                        hipFuncAttributeMaxDynamicSharedMemorySize, 89088);

    small_prep<<<1608, 256, 0, stream>>>(w, wbuf, xbuf);
    cast_transpose_x<<<dim3(98, 2, 32), dim3(256), 0, stream>>>(x, xbuf);
    conv_gemm<<<448, 512, 89088, stream>>>(xbuf, wbuf, bias, out);
}